// Round 21
// baseline (43.450 us; speedup 1.0000x reference)
//
#include <hip/hip_runtime.h>

#define TPB 64
#define KCH 8                  // chunks per block
#define CHR 64                 // rows per chunk
#define BLKR (KCH * CHR)       // 512 rows per block
#define LOG2E 1.44269504088896340736f

typedef _Float16 half8 __attribute__((ext_vector_type(8)));
typedef _Float16 half4 __attribute__((ext_vector_type(4)));
typedef __fp16  fp16x2 __attribute__((ext_vector_type(2)));
typedef float f32x4 __attribute__((ext_vector_type(4)));

__device__ __forceinline__ half8 pack8(float4 lo, float4 hi) {
    union { fp16x2 p[4]; half8 h; } u;
    u.p[0] = __builtin_amdgcn_cvt_pkrtz(lo.x, lo.y);
    u.p[1] = __builtin_amdgcn_cvt_pkrtz(lo.z, lo.w);
    u.p[2] = __builtin_amdgcn_cvt_pkrtz(hi.x, hi.y);
    u.p[3] = __builtin_amdgcn_cvt_pkrtz(hi.z, hi.w);
    return u.h;
}
__device__ __forceinline__ half4 cvt4(float4 v) {
    union { fp16x2 p[2]; half4 h; } u;
    u.p[0] = __builtin_amdgcn_cvt_pkrtz(v.x, v.y);
    u.p[1] = __builtin_amdgcn_cvt_pkrtz(v.z, v.w);
    return u.h;
}
__device__ __forceinline__ half8 cat8(half4 a, half4 b) {
    union { half4 q[2]; half8 o; } u;
    u.q[0] = a; u.q[1] = b;
    return u.o;
}
__device__ __forceinline__ void nt_store4(float* p, float4 v) {
    union { float4 s; f32x4 e; } u;
    u.s = v;
    __builtin_nontemporal_store(u.e, (f32x4*)p);
}

// ---- ws layout (h-first k-map) ----
// halfs: 6 tiles x 512 (r, z, n_i, n_h, hp-identity, A2) = 6144 B
// byte 6144: float4 bias[16] {b_r, b_z, b_ni, b_nh} (exp2-prescaled)
// MAIN k-map: k0-15 = h[0..15], k16-19 = xa(z0,z1,z2,act), k20-31 = 0
// hp identity: B[k][n] = (k==n), k<16. A2: k0-15 = W rows, k20 = bias slot.

__global__ __launch_bounds__(64) void prep_kernel(
    const float* __restrict__ W_ih, const float* __restrict__ W_hh,
    const float* __restrict__ b_ih, const float* __restrict__ b_hh,
    const float* __restrict__ W_mu, const float* __restrict__ b_mu,
    const float* __restrict__ W_lv, const float* __restrict__ b_lv,
    void* __restrict__ wsv)
{
    _Float16* wsB = (_Float16*)wsv;
    const int l = threadIdx.x;
    const int col = l & 15, kg = l >> 4;

    #pragma unroll
    for (int t = 0; t < 4; ++t) {
        const int gate = (t == 0) ? col : (t == 1) ? (16 + col) : (32 + col);
        const float scale = (t <= 1) ? -LOG2E : -2.0f * LOG2E;
        #pragma unroll
        for (int i = 0; i < 8; ++i) {
            const int k = kg * 8 + i;
            float v = 0.f;
            if (t <= 1) {
                if (k < 16)            v = W_hh[gate * 16 + k];
                else if (k < 20)       v = W_ih[gate * 4 + (k - 16)];
            } else if (t == 2) {
                if (k >= 16 && k < 20) v = W_ih[gate * 4 + (k - 16)];
            } else {
                if (k < 16)            v = W_hh[gate * 16 + k];
            }
            wsB[t * 512 + l * 8 + i] = (_Float16)(v * scale);
        }
    }
    #pragma unroll
    for (int i = 0; i < 8; ++i) {
        const int k = kg * 8 + i;
        wsB[4 * 512 + l * 8 + i] = (_Float16)((k == col) ? 1.f : 0.f);
    }
    #pragma unroll
    for (int i = 0; i < 8; ++i) {
        const int k = kg * 8 + i;
        const int m = col;
        float v = 0.f;
        if (m < 3) {
            if (k < 16)       v = W_mu[m * 16 + k];
            else if (k == 20) v = b_mu[m];
        } else if (m < 6) {
            if (k < 16)       v = W_lv[(m - 3) * 16 + k];
            else if (k == 20) v = b_lv[m - 3];
        }
        wsB[5 * 512 + l * 8 + i] = (_Float16)v;
    }
    if (l < 16) {
        float4* b4 = (float4*)((char*)wsv + 6144);
        b4[l] = make_float4(-LOG2E * (b_ih[l] + b_hh[l]),
                            -LOG2E * (b_ih[16 + l] + b_hh[16 + l]),
                            -2.0f * LOG2E * b_ih[32 + l],
                            -2.0f * LOG2E * b_hh[32 + l]);
    }
}

template<bool EXACT>
__global__ __launch_bounds__(TPB, 4) void rssm_kernel(
    const float* __restrict__ prev_z,   // [B,3]
    const float* __restrict__ action,   // [B,1]
    const float* __restrict__ prev_h,   // [B,16]
    const void*  __restrict__ wsv,
    float* __restrict__ out_mu,         // [B,3]
    float* __restrict__ out_lv,         // [B,3]
    float* __restrict__ out_h,          // [B,16]
    int B)
{
    __shared__ __align__(16) float Hb[2][64 * 16];   // 4 KB per buffer
    __shared__ __align__(16) float XA[BLKR * 4];     // 8 KB: whole-block xa
    __shared__ float MU[192], LV[192];

    const int lane = threadIdx.x;
    const int col = lane & 15, kg = lane >> 4;
    const size_t bbase = (size_t)blockIdx.x * BLKR;
    if (!EXACT && bbase >= (size_t)B) return;

    // ---- wave-invariant fragments ----
    const half8* Bp = (const half8*)wsv;
    const half8 bR  = Bp[lane];
    const half8 bZ  = Bp[64 + lane];
    const half8 bNi = Bp[128 + lane];
    const half8 bNh = Bp[192 + lane];
    const half8 bHp = Bp[256 + lane];
    const half8 a2  = Bp[320 + lane];
    const float4 bias = ((const float4*)((const char*)wsv + 6144))[col];

    half4 zz; zz[0] = zz[1] = zz[2] = zz[3] = (_Float16)0.f;

    // ---- per-chunk compute from buffer cb; xa from XA[cloc...] ----
    auto compute_chunk = [&](int cb, int cloc, size_t cbase) {
        float* Hc = Hb[cb];
        #pragma unroll
        for (int t = 0; t < 4; ++t) {
            half8 a;
            if (kg < 2) {
                const float4 p0 = *(const float4*)&Hc[(t * 16 + col) * 16 + kg * 8];
                const float4 p1 = *(const float4*)&Hc[(t * 16 + col) * 16 + kg * 8 + 4];
                a = pack8(p0, p1);
            } else if (kg == 2) {
                const float4 x4 = *(const float4*)&XA[(cloc + t * 16 + col) * 4];
                a = cat8(cvt4(x4), zz);
            } else {
                a = cat8(zz, zz);
            }

            f32x4 accR  = {bias.x, bias.x, bias.x, bias.x};
            f32x4 accZ  = {bias.y, bias.y, bias.y, bias.y};
            f32x4 accNi = {bias.z, bias.z, bias.z, bias.z};
            f32x4 accNh = {bias.w, bias.w, bias.w, bias.w};
            f32x4 accHp = {0.f, 0.f, 0.f, 0.f};
            accR  = __builtin_amdgcn_mfma_f32_16x16x32_f16(a, bR,  accR,  0, 0, 0);
            accZ  = __builtin_amdgcn_mfma_f32_16x16x32_f16(a, bZ,  accZ,  0, 0, 0);
            accNi = __builtin_amdgcn_mfma_f32_16x16x32_f16(a, bNi, accNi, 0, 0, 0);
            accNh = __builtin_amdgcn_mfma_f32_16x16x32_f16(a, bNh, accNh, 0, 0, 0);
            accHp = __builtin_amdgcn_mfma_f32_16x16x32_f16(a, bHp, accHp, 0, 0, 0);

            #pragma unroll
            for (int q = 0; q < 4; ++q) {
                const float r  = __builtin_amdgcn_rcpf(1.0f + __builtin_amdgcn_exp2f(accR[q]));
                const float z  = __builtin_amdgcn_rcpf(1.0f + __builtin_amdgcn_exp2f(accZ[q]));
                const float ta = fmaf(r, accNh[q], accNi[q]);
                const float n  = fmaf(2.0f,
                                      __builtin_amdgcn_rcpf(1.0f + __builtin_amdgcn_exp2f(ta)),
                                      -1.0f);
                const float hv = fmaf(z, accHp[q] - n, n);       // (1-z)*n + z*h
                Hc[(t * 16 + kg * 4 + q) * 16 + col] = hv;
            }

            half8 b2;
            if (kg < 2) {
                const float4 h0 = *(const float4*)&Hc[(t * 16 + col) * 16 + kg * 8];
                const float4 h1 = *(const float4*)&Hc[(t * 16 + col) * 16 + kg * 8 + 4];
                b2 = pack8(h0, h1);
            } else {
                b2 = cat8(zz, zz);
                if (kg == 2) b2[4] = (_Float16)1.0f;             // k=20 bias slot
            }
            f32x4 acc2 = {0.f, 0.f, 0.f, 0.f};
            acc2 = __builtin_amdgcn_mfma_f32_16x16x32_f16(a2, b2, acc2, 0, 0, 0);

            const int mr = (t * 16 + col) * 3;
            if (kg == 0) {
                MU[mr + 0] = acc2[0];
                MU[mr + 1] = acc2[1];
                MU[mr + 2] = acc2[2];
                LV[mr + 0] = fminf(fmaxf(acc2[3], -5.0f), 5.0f);
            } else if (kg == 1) {
                LV[mr + 1] = fminf(fmaxf(acc2[0], -5.0f), 5.0f);
                LV[mr + 2] = fminf(fmaxf(acc2[1], -5.0f), 5.0f);
            }

            {
                const int r = lane >> 2, w = lane & 3;
                const float4 hv4 = *(const float4*)&Hc[(t * 16 + r) * 16 + w * 4];
                const size_t orow = cbase + t * 16 + r;
                if (EXACT || orow < (size_t)B)
                    nt_store4(&out_h[orow * 16 + w * 4], hv4);
            }
        }

        if (lane < 48) {
            const size_t gi = cbase * 3 + lane * 4;
            if (EXACT || gi + 3 < (size_t)B * 3) {
                nt_store4(&out_mu[gi], *(const float4*)&MU[lane * 4]);
                nt_store4(&out_lv[gi], *(const float4*)&LV[lane * 4]);
            }
        }
    };

    if constexpr (EXACT) {
        // ---- prologue: stage ALL xa for this block via normal loads ----
        #pragma unroll
        for (int i = 0; i < 8; ++i) {
            const int rl = i * 64 + lane;              // 0..511
            const size_t gr = bbase + rl;
            *(float4*)&XA[rl * 4] =
                make_float4(prev_z[gr * 3 + 0], prev_z[gr * 3 + 1],
                            prev_z[gr * 3 + 2], action[gr]);
        }
        // drain xa loads so vmcnt counting below is exact
        asm volatile("s_waitcnt vmcnt(0)" ::: "memory");
        __builtin_amdgcn_sched_barrier(0);

        // ---- async issue of one chunk's h: exactly 4 glls (16 B, proven) ----
        auto issue = [&](int c) {
            const size_t cbase = bbase + (size_t)c * CHR;
            const float4* hg = (const float4*)(prev_h + cbase * 16);
            #pragma unroll
            for (int i = 0; i < 4; ++i)
                __builtin_amdgcn_global_load_lds(
                    (const void*)(hg + i * 64 + lane),
                    (void*)&Hb[c & 1][i * 256], 16, 0, 0);
        };

        issue(0);
        issue(1);
        #pragma unroll 1
        for (int c = 0; c < KCH; ++c) {
            if (c < KCH - 1) {
                // newest 4 outstanding = chunk c+1's glls; all older
                // (chunk c glls + prior NT stores) drained -> c's data ready
                asm volatile("s_waitcnt vmcnt(4)" ::: "memory");
            } else {
                asm volatile("s_waitcnt vmcnt(0)" ::: "memory");
            }
            __builtin_amdgcn_sched_barrier(0);
            compute_chunk(c & 1, c * CHR, bbase + (size_t)c * CHR);
            if (c + 2 < KCH) {
                __builtin_amdgcn_sched_barrier(0);   // keep issue after reads
                issue(c + 2);
            }
        }
    } else {
        const float4* hg = (const float4*)prev_h;
        #pragma unroll 1
        for (int c = 0; c < KCH; ++c) {
            const size_t cbase = bbase + (size_t)c * CHR;
            if (cbase >= (size_t)B) break;
            #pragma unroll
            for (int i = 0; i < 4; ++i) {
                const size_t gi = min(cbase * 4 + i * 64 + lane, (size_t)B * 4 - 1);
                *(float4*)&Hb[c & 1][i * 256 + lane * 4] = hg[gi];
            }
            const size_t zr = min(cbase + lane, (size_t)B - 1);
            *(float4*)&XA[(c * CHR + lane) * 4] =
                make_float4(prev_z[zr * 3 + 0], prev_z[zr * 3 + 1],
                            prev_z[zr * 3 + 2], action[zr]);
            compute_chunk(c & 1, c * CHR, cbase);
        }
    }
}

extern "C" void kernel_launch(void* const* d_in, const int* in_sizes, int n_in,
                              void* d_out, int out_size, void* d_ws, size_t ws_size,
                              hipStream_t stream) {
    const float* prev_z = (const float*)d_in[0];
    const float* action = (const float*)d_in[1];
    const float* prev_h = (const float*)d_in[2];
    const float* W_ih   = (const float*)d_in[3];
    const float* W_hh   = (const float*)d_in[4];
    const float* b_ih   = (const float*)d_in[5];
    const float* b_hh   = (const float*)d_in[6];
    const float* W_mu   = (const float*)d_in[7];
    const float* b_mu   = (const float*)d_in[8];
    const float* W_lv   = (const float*)d_in[9];
    const float* b_lv   = (const float*)d_in[10];

    const int B = in_sizes[0] / 3;
    float* out    = (float*)d_out;
    float* out_mu = out;
    float* out_lv = out + (size_t)3 * B;
    float* out_h  = out + (size_t)6 * B;

    prep_kernel<<<1, 64, 0, stream>>>(W_ih, W_hh, b_ih, b_hh,
                                      W_mu, b_mu, W_lv, b_lv, d_ws);

    const int blocks = (B + BLKR - 1) / BLKR;
    if ((B % BLKR) == 0)
        rssm_kernel<true><<<blocks, TPB, 0, stream>>>(prev_z, action, prev_h, d_ws,
                                                      out_mu, out_lv, out_h, B);
    else
        rssm_kernel<false><<<blocks, TPB, 0, stream>>>(prev_z, action, prev_h, d_ws,
                                                       out_mu, out_lv, out_h, B);
}